// Round 17
// baseline (144.714 us; speedup 1.0000x reference)
//
#include <hip/hip_runtime.h>

#define N_PIX 4096
#define IMG_W 64
#define C_IN 256
#define TD3 768
#define N_B 8
#define N_G 64
#define C_OUT 256

typedef _Float16 f16;
typedef _Float16 half8 __attribute__((ext_vector_type(8)));
typedef _Float16 f16x4 __attribute__((ext_vector_type(4)));
typedef _Float16 f16x2 __attribute__((ext_vector_type(2)));
typedef float f32x4 __attribute__((ext_vector_type(4)));

// ---------------------------------------------------------------------------
// k_prep: MERGED weight-convert + x-transpose.
// z < 8:  x -> xT (hi,lo) f16. hi/lo REQUIRED for q path (R6/R7).
// z == 8: w_qkv -> wqq hi/lo (q) / wqkv hi (kv, 1-term safe); w_proj -> f16.
// ---------------------------------------------------------------------------
__global__ __launch_bounds__(256) void k_prep(const float* __restrict__ x,
                                              const float* __restrict__ wq,
                                              const float* __restrict__ wp,
                                              f16* __restrict__ xh,
                                              f16* __restrict__ xl,
                                              f16* __restrict__ wqq_h,
                                              f16* __restrict__ wqq_l,
                                              f16* __restrict__ wqkv,
                                              f16* __restrict__ wph) {
  const int t = threadIdx.x;
  if (blockIdx.z == 8) {
    const int bid = blockIdx.x + 64 * blockIdx.y;
    for (int i = bid * 256 + t; i < TD3 * C_IN + C_OUT * 512; i += 65536) {
      if (i < TD3 * C_IN) {
        const int r = i >> 8, k = i & 255;
        const float v = wq[i];
        const f16 h = (f16)v;
        const int g = r / 24, j = r % 24;
        if (j < 8) {
          const int qi = g * 8 + j;
          wqq_h[qi * 256 + k] = h;
          wqq_l[qi * 256 + k] = (f16)(v - (float)h);
        } else {
          const int kvi = g * 16 + (j - 8);
          wqkv[kvi * 256 + k] = h;
        }
      } else {
        const int j = i - TD3 * C_IN;
        wph[j] = (f16)wp[j];
      }
    }
    return;
  }
  __shared__ float st[64][65];
  const int n0 = blockIdx.x * 64;
  const int k0 = blockIdx.y * 64;
  const size_t b = blockIdx.z;
  const float* xb = x + b * (size_t)C_IN * N_PIX;
#pragma unroll
  for (int i = 0; i < 16; ++i) {
    const int idx = t + i * 256;
    const int r = idx >> 6, c = idx & 63;
    st[r][c] = xb[(size_t)(k0 + r) * N_PIX + n0 + c];
  }
  __syncthreads();
#pragma unroll
  for (int i = 0; i < 8; ++i) {
    const int idx = t + i * 256;
    const int n = idx >> 5, k2 = (idx & 31) * 2;
    const float v0 = st[k2][n], v1 = st[k2 + 1][n];
    const f16 h0 = (f16)v0, h1 = (f16)v1;
    const size_t o = (b * N_PIX + n0 + n) * C_IN + k0 + k2;
    *(f16x2*)(xh + o) = (f16x2){h0, h1};
    *(f16x2*)(xl + o) = (f16x2){(f16)(v0 - (float)h0), (f16)(v1 - (float)h1)};
  }
}

// ---------------------------------------------------------------------------
// k_gemmqkv: MERGED q-GEMM (3-term, BK=32) + kv-GEMM (1-term, BK=64).
// ---------------------------------------------------------------------------
__global__ __launch_bounds__(256) void k_gemmqkv(const f16* __restrict__ Ah,
                                                 const f16* __restrict__ Al,
                                                 const f16* __restrict__ Akv,
                                                 const f16* __restrict__ Bh,
                                                 const f16* __restrict__ Bl,
                                                 f16* __restrict__ C) {
  __shared__ f16 sm[2][16384];
  const int t = threadIdx.x;
  const int lane = t & 63;
  const int w = t >> 6;

  if (blockIdx.x < 512) {
    const int bid = blockIdx.x;
    const int swz = (bid & 7) * 64 + (bid >> 3);
    const int mt = swz % 2;
    const int rest = swz / 2;
    const int nt = rest & 31;
    const size_t bz = rest >> 5;
    const int m0 = mt * 128;
    const int n0 = nt * 128;
    const int K = C_IN;

    const f16* Bhb = Bh + bz * (size_t)N_PIX * K;
    const f16* Blb = Bl + bz * (size_t)N_PIX * K;
    f16* Cb = C + bz * (size_t)TD3 * N_PIX;

    f32x4 acc[4][4];
#pragma unroll
    for (int i = 0; i < 4; ++i)
#pragma unroll
      for (int j = 0; j < 4; ++j) acc[i][j] = (f32x4){0.f, 0.f, 0.f, 0.f};

    const int wm = w >> 1, wn = w & 1;
    const int fr = lane & 15;
    const int fk = (lane >> 4) * 8;

    const f16* gsrc[8];
    int sslot[8];
#pragma unroll
    for (int i = 0; i < 8; ++i) {
      const int s = w + i * 4;
      const int frag = s & 7;
      const f16* base;
      int row0;
      if (s < 8) {
        base = Ah; row0 = m0;
      } else if (s < 16) {
        base = Al; row0 = m0;
      } else if (s < 24) {
        base = Bhb; row0 = n0;
      } else {
        base = Blb; row0 = n0;
      }
      gsrc[i] = base + (size_t)(row0 + frag * 16 + fr) * K + fk;
      sslot[i] = s * 512;
    }

#pragma unroll
    for (int i = 0; i < 8; ++i)
      __builtin_amdgcn_global_load_lds(
          (const __attribute__((address_space(1))) unsigned int*)gsrc[i],
          (__attribute__((address_space(3))) unsigned int*)&sm[0][sslot[i]], 16, 0, 0);

    int cur = 0;
    for (int tt = 0; tt < 8; ++tt) {
      if (tt + 1 < 8) {
#pragma unroll
        for (int i = 0; i < 8; ++i)
          __builtin_amdgcn_global_load_lds(
              (const __attribute__((address_space(1))) unsigned int*)(gsrc[i] + (tt + 1) * 32),
              (__attribute__((address_space(3))) unsigned int*)&sm[cur ^ 1][sslot[i]], 16, 0, 0);
        asm volatile("s_waitcnt vmcnt(8)" ::: "memory");
      } else {
        asm volatile("s_waitcnt vmcnt(0)" ::: "memory");
      }
      __builtin_amdgcn_s_barrier();
      const f16* smb = sm[cur];
      half8 ah[4], al[4], bh[4], bl[4];
#pragma unroll
      for (int mi = 0; mi < 4; ++mi) {
        ah[mi] = *(const half8*)&smb[(wm * 4 + mi) * 512 + lane * 8];
        al[mi] = *(const half8*)&smb[(8 + wm * 4 + mi) * 512 + lane * 8];
      }
#pragma unroll
      for (int ni = 0; ni < 4; ++ni) {
        bh[ni] = *(const half8*)&smb[(16 + wn * 4 + ni) * 512 + lane * 8];
        bl[ni] = *(const half8*)&smb[(24 + wn * 4 + ni) * 512 + lane * 8];
      }
#pragma unroll
      for (int mi = 0; mi < 4; ++mi)
#pragma unroll
        for (int ni = 0; ni < 4; ++ni) {
          acc[mi][ni] = __builtin_amdgcn_mfma_f32_16x16x32_f16(ah[mi], bh[ni], acc[mi][ni], 0, 0, 0);
          acc[mi][ni] = __builtin_amdgcn_mfma_f32_16x16x32_f16(ah[mi], bl[ni], acc[mi][ni], 0, 0, 0);
          acc[mi][ni] = __builtin_amdgcn_mfma_f32_16x16x32_f16(al[mi], bh[ni], acc[mi][ni], 0, 0, 0);
        }
      __builtin_amdgcn_s_barrier();
      cur ^= 1;
    }
    const int cr = (lane >> 4) * 4;
    const int cc = lane & 15;
#pragma unroll
    for (int mi = 0; mi < 4; ++mi)
#pragma unroll
      for (int ni = 0; ni < 4; ++ni) {
#pragma unroll
        for (int r = 0; r < 4; ++r) {
          const int row = m0 + wm * 64 + mi * 16 + cr + r;
          const int ch = (row >> 3) * 24 + (row & 7);
          Cb[(size_t)ch * N_PIX + n0 + wn * 64 + ni * 16 + cc] = (f16)acc[mi][ni][r];
        }
      }
  } else {
    const int bid = blockIdx.x - 512;
    const int swz = (bid & 7) * 128 + (bid >> 3);
    const int mt = swz % 4;
    const int rest = swz / 4;
    const int nt = rest & 31;
    const size_t bz = rest >> 5;
    const int m0 = mt * 128;
    const int n0 = nt * 128;
    const int K = C_IN;

    const f16* Bb = Bh + bz * (size_t)N_PIX * K;
    f16* Cb = C + bz * (size_t)TD3 * N_PIX;

    f32x4 acc[4][4];
#pragma unroll
    for (int i = 0; i < 4; ++i)
#pragma unroll
      for (int j = 0; j < 4; ++j) acc[i][j] = (f32x4){0.f, 0.f, 0.f, 0.f};

    const int wm = w >> 1, wn = w & 1;
    const int fr2 = lane >> 3;
    const int fko = (lane & 7) * 8;
    const f16* gsrc[4][2];
    int sslot[4][2];
#pragma unroll
    for (int i = 0; i < 4; ++i) {
      const int s = w + i * 4;
      const int frag = s & 7;
      const f16* base = (s < 8) ? Akv : Bb;
      const int row0 = (s < 8) ? m0 : n0;
#pragma unroll
      for (int j = 0; j < 2; ++j) {
        gsrc[i][j] = base + (size_t)(row0 + frag * 16 + j * 8 + fr2) * K + fko;
        sslot[i][j] = s * 1024 + j * 512;
      }
    }

#pragma unroll
    for (int i = 0; i < 4; ++i)
#pragma unroll
      for (int j = 0; j < 2; ++j)
        __builtin_amdgcn_global_load_lds(
            (const __attribute__((address_space(1))) unsigned int*)gsrc[i][j],
            (__attribute__((address_space(3))) unsigned int*)&sm[0][sslot[i][j]], 16, 0, 0);

    int cur = 0;
    for (int tt = 0; tt < 4; ++tt) {
      if (tt + 1 < 4) {
#pragma unroll
        for (int i = 0; i < 4; ++i)
#pragma unroll
          for (int j = 0; j < 2; ++j)
            __builtin_amdgcn_global_load_lds(
                (const __attribute__((address_space(1))) unsigned int*)(gsrc[i][j] + (tt + 1) * 64),
                (__attribute__((address_space(3))) unsigned int*)&sm[cur ^ 1][sslot[i][j]], 16, 0, 0);
        asm volatile("s_waitcnt vmcnt(8)" ::: "memory");
      } else {
        asm volatile("s_waitcnt vmcnt(0)" ::: "memory");
      }
      __builtin_amdgcn_s_barrier();
      const f16* smb = sm[cur];
      const int fb = (lane & 15) * 64 + (lane >> 4) * 8;
      half8 av[4][2], bv[4][2];
#pragma unroll
      for (int mi = 0; mi < 4; ++mi)
#pragma unroll
        for (int kk = 0; kk < 2; ++kk)
          av[mi][kk] = *(const half8*)&smb[(wm * 4 + mi) * 1024 + fb + kk * 32];
#pragma unroll
      for (int ni = 0; ni < 4; ++ni)
#pragma unroll
        for (int kk = 0; kk < 2; ++kk)
          bv[ni][kk] = *(const half8*)&smb[(8 + wn * 4 + ni) * 1024 + fb + kk * 32];
#pragma unroll
      for (int kk = 0; kk < 2; ++kk)
#pragma unroll
        for (int mi = 0; mi < 4; ++mi)
#pragma unroll
          for (int ni = 0; ni < 4; ++ni)
            acc[mi][ni] = __builtin_amdgcn_mfma_f32_16x16x32_f16(av[mi][kk], bv[ni][kk], acc[mi][ni], 0, 0, 0);
      __builtin_amdgcn_s_barrier();
      cur ^= 1;
    }
    const int cr = (lane >> 4) * 4;
    const int cc = lane & 15;
#pragma unroll
    for (int mi = 0; mi < 4; ++mi)
#pragma unroll
      for (int ni = 0; ni < 4; ++ni) {
#pragma unroll
        for (int r = 0; r < 4; ++r) {
          const int row = m0 + wm * 64 + mi * 16 + cr + r;
          const int ch = (row >> 4) * 24 + 8 + (row & 15);
          Cb[(size_t)ch * N_PIX + n0 + wn * 64 + ni * 16 + cc] = (f16)acc[mi][ni][r];
        }
      }
  }
}

// ---------------------------------------------------------------------------
// k_gemm1: out = A[256][512] * B[b][4096][512]^T, 1-term f16, BK=64.
// ---------------------------------------------------------------------------
__global__ __launch_bounds__(256) void k_gemm1(const f16* __restrict__ A,
                                               const f16* __restrict__ B,
                                               float* __restrict__ C,
                                               int M, int K) {
  __shared__ f16 sm[2][16 * 1024];
  const int t = threadIdx.x;
  const int lane = t & 63;
  const int w = t >> 6;

  const int per = gridDim.x >> 3;
  const int swz = (blockIdx.x & 7) * per + (blockIdx.x >> 3);
  const int mtiles = M >> 7;
  const int mt = swz % mtiles;
  const int rest = swz / mtiles;
  const int nt = rest & 31;
  const size_t bz = rest >> 5;
  const int m0 = mt * 128;
  const int n0 = nt * 128;

  const f16* Bb = B + bz * (size_t)N_PIX * K;
  float* Cb = C + bz * (size_t)M * N_PIX;

  f32x4 acc[4][4];
#pragma unroll
  for (int i = 0; i < 4; ++i)
#pragma unroll
    for (int j = 0; j < 4; ++j) acc[i][j] = (f32x4){0.f, 0.f, 0.f, 0.f};

  const int wm = w >> 1, wn = w & 1;
  const int fr2 = lane >> 3;
  const int fko = (lane & 7) * 8;
  const f16* gsrc[4][2];
  int sslot[4][2];
#pragma unroll
  for (int i = 0; i < 4; ++i) {
    const int s = w + i * 4;
    const int frag = s & 7;
    const f16* base = (s < 8) ? A : Bb;
    const int row0 = (s < 8) ? m0 : n0;
#pragma unroll
    for (int j = 0; j < 2; ++j) {
      gsrc[i][j] = base + (size_t)(row0 + frag * 16 + j * 8 + fr2) * K + fko;
      sslot[i][j] = s * 1024 + j * 512;
    }
  }

#pragma unroll
  for (int i = 0; i < 4; ++i)
#pragma unroll
    for (int j = 0; j < 2; ++j)
      __builtin_amdgcn_global_load_lds(
          (const __attribute__((address_space(1))) unsigned int*)gsrc[i][j],
          (__attribute__((address_space(3))) unsigned int*)&sm[0][sslot[i][j]], 16, 0, 0);

  const int ntk = K / 64;
  int cur = 0;
  for (int tt = 0; tt < ntk; ++tt) {
    if (tt + 1 < ntk) {
#pragma unroll
      for (int i = 0; i < 4; ++i)
#pragma unroll
        for (int j = 0; j < 2; ++j)
          __builtin_amdgcn_global_load_lds(
              (const __attribute__((address_space(1))) unsigned int*)(gsrc[i][j] + (tt + 1) * 64),
              (__attribute__((address_space(3))) unsigned int*)&sm[cur ^ 1][sslot[i][j]], 16, 0, 0);
      asm volatile("s_waitcnt vmcnt(8)" ::: "memory");
    } else {
      asm volatile("s_waitcnt vmcnt(0)" ::: "memory");
    }
    __builtin_amdgcn_s_barrier();
    const f16* smb = sm[cur];
    const int fb = (lane & 15) * 64 + (lane >> 4) * 8;
    half8 av[4][2], bv[4][2];
#pragma unroll
    for (int mi = 0; mi < 4; ++mi)
#pragma unroll
      for (int kk = 0; kk < 2; ++kk)
        av[mi][kk] = *(const half8*)&smb[(wm * 4 + mi) * 1024 + fb + kk * 32];
#pragma unroll
    for (int ni = 0; ni < 4; ++ni)
#pragma unroll
      for (int kk = 0; kk < 2; ++kk)
        bv[ni][kk] = *(const half8*)&smb[(8 + wn * 4 + ni) * 1024 + fb + kk * 32];
#pragma unroll
    for (int kk = 0; kk < 2; ++kk)
#pragma unroll
      for (int mi = 0; mi < 4; ++mi)
#pragma unroll
        for (int ni = 0; ni < 4; ++ni)
          acc[mi][ni] = __builtin_amdgcn_mfma_f32_16x16x32_f16(av[mi][kk], bv[ni][kk], acc[mi][ni], 0, 0, 0);
    __builtin_amdgcn_s_barrier();
    cur ^= 1;
  }
  const int cr = (lane >> 4) * 4;
  const int cc = lane & 15;
#pragma unroll
  for (int mi = 0; mi < 4; ++mi)
#pragma unroll
    for (int ni = 0; ni < 4; ++ni) {
      float* p = Cb + (size_t)(m0 + wm * 64 + mi * 16 + cr) * N_PIX + n0 + wn * 64 + ni * 16 + cc;
#pragma unroll
      for (int r = 0; r < 4; ++r) p[(size_t)r * N_PIX] = acc[mi][ni][r];
    }
}

// ---------------------------------------------------------------------------
// k_dw: depthwise 5x5 (split form — fused dw+pw regressed twice: R3, R10).
// ---------------------------------------------------------------------------
__global__ __launch_bounds__(256) void k_dw(const f16* __restrict__ qkv,
                                            const float* __restrict__ wdw,
                                            f16* __restrict__ dw) {
  __shared__ float sin_[68][72];
  const int t = threadIdx.x;
  const int bc = blockIdx.x;
  const int ch = bc % TD3;
  const f16* src = qkv + (size_t)bc * N_PIX;

  for (int i = t; i < 68 * 72 / 4; i += 256) ((f32x4*)sin_)[i] = (f32x4){0.f, 0.f, 0.f, 0.f};
  float wreg[25];
#pragma unroll
  for (int i = 0; i < 25; ++i) wreg[i] = wdw[(size_t)ch * 25 + i];
  __syncthreads();
  for (int i = t; i < 512; i += 256) {
    const int r = i >> 3, c8 = (i & 7) * 8;
    const half8 p = *(const half8*)(src + r * 64 + c8);
    f32x4 lo = {(float)p[0], (float)p[1], (float)p[2], (float)p[3]};
    f32x4 hi = {(float)p[4], (float)p[5], (float)p[6], (float)p[7]};
    *(f32x4*)&sin_[r + 2][c8 + 4] = lo;
    *(f32x4*)&sin_[r + 2][c8 + 8] = hi;
  }
  __syncthreads();

  const int c = t & 63;
  const int rg = t >> 6;
  const int r0 = rg * 16;
  float win[5][5];
#pragma unroll
  for (int r = 0; r < 4; ++r)
#pragma unroll
    for (int j = 0; j < 5; ++j) win[r][j] = sin_[r0 + r][c + 2 + j];
#pragma unroll
  for (int orow = 0; orow < 16; ++orow) {
    const int slot = (orow + 4) % 5;
#pragma unroll
    for (int j = 0; j < 5; ++j) win[slot][j] = sin_[r0 + orow + 4][c + 2 + j];
    float s = 0.f;
#pragma unroll
    for (int dr = 0; dr < 5; ++dr) {
      const int rs = (orow + dr) % 5;
#pragma unroll
      for (int dc = 0; dc < 5; ++dc) s = fmaf(win[rs][dc], wreg[dr * 5 + dc], s);
    }
    dw[(size_t)bc * N_PIX + (r0 + orow) * 64 + c] = (f16)s;
  }
}

// ---------------------------------------------------------------------------
// k_kv: kv[b][g][72]. R17: k_pw eliminated — for g>=32, k's pw is inlined
// per pixel (relu inside the sum); v's pw is HOISTED out of the pixel sum
// (linear): accumulate vs raw dwv, post-multiply the reduced 8x9 by Wv^T.
// fp32 throughout (removes the old f16 agg rounding -> closer to reference).
// ---------------------------------------------------------------------------
__global__ __launch_bounds__(256, 1) void k_kv(const f16* __restrict__ qkv,
                                               const f16* __restrict__ dw,
                                               const float* __restrict__ wpw,
                                               float* __restrict__ kvbuf) {
  const int t = threadIdx.x;
  const int g = blockIdx.x;
  const int b = blockIdx.y;
  const bool pwp = (g >= 32);
  __shared__ float swpk[64], swpv[64];
  const f16 *kc, *vc;
  if (pwp) {
    const int gg = g - 32;
    if (t < 64) swpk[t] = wpw[(size_t)(gg * 3 + 1) * 64 + t];
    else if (t < 128) swpv[t - 64] = wpw[(size_t)(gg * 3 + 2) * 64 + (t - 64)];
    kc = dw + ((size_t)b * TD3 + gg * 24 + 8) * N_PIX;
    vc = dw + ((size_t)b * TD3 + gg * 24 + 16) * N_PIX;
    __syncthreads();
  } else {
    kc = qkv + ((size_t)b * TD3 + g * 24 + 8) * N_PIX;
    vc = qkv + ((size_t)b * TD3 + g * 24 + 16) * N_PIX;
  }

  float acc[72];
#pragma unroll
  for (int i = 0; i < 72; i++) acc[i] = 0.f;

  for (int i = 0; i < N_PIX / 256; i++) {
    const int n = t + i * 256;
    float kd[8], ve[8];
    if (pwp) {
      float dk[8];
#pragma unroll
      for (int d = 0; d < 8; d++) dk[d] = (float)kc[(size_t)d * N_PIX + n];
#pragma unroll
      for (int e = 0; e < 8; e++) ve[e] = (float)vc[(size_t)e * N_PIX + n];
#pragma unroll
      for (int d = 0; d < 8; d++) {
        float s = 0.f;
#pragma unroll
        for (int ic = 0; ic < 8; ic++) s = fmaf(dk[ic], swpk[d * 8 + ic], s);
        kd[d] = fmaxf(s, 0.f);
      }
    } else {
#pragma unroll
      for (int d = 0; d < 8; d++) kd[d] = fmaxf((float)kc[(size_t)d * N_PIX + n], 0.f);
#pragma unroll
      for (int e = 0; e < 8; e++) ve[e] = (float)vc[(size_t)e * N_PIX + n];
    }
#pragma unroll
    for (int d = 0; d < 8; d++) {
#pragma unroll
      for (int e = 0; e < 8; e++) acc[d * 9 + e] = fmaf(kd[d], ve[e], acc[d * 9 + e]);
      acc[d * 9 + 8] += kd[d];
    }
  }

  const int lane = t & 63, wv = t >> 6;
#pragma unroll
  for (int i = 0; i < 72; i++) acc[i] += __shfl_xor(acc[i], 32, 64);
  const int hi = lane >> 5;
  float r[36];
#pragma unroll
  for (int i = 0; i < 36; i++) r[i] = hi ? acc[36 + i] : acc[i];
#pragma unroll
  for (int off = 16; off >= 1; off >>= 1) {
#pragma unroll
    for (int i = 0; i < 36; i++) r[i] += __shfl_xor(r[i], off, 64);
  }
  __shared__ float red[4][72];
  __shared__ float fin[72];
  if (lane == 0 || lane == 32) {
#pragma unroll
    for (int i = 0; i < 36; i++) red[wv][hi * 36 + i] = r[i];
  }
  __syncthreads();
  if (t < 72) fin[t] = red[0][t] + red[1][t] + red[2][t] + red[3][t];
  __syncthreads();
  if (t < 72) {
    const int d = t / 9, e = t % 9;
    float o;
    if (!pwp || e == 8) {
      o = fin[t];
    } else {
      o = 0.f;
#pragma unroll
      for (int ic = 0; ic < 8; ic++) o = fmaf(fin[d * 9 + ic], swpv[e * 8 + ic], o);
    }
    kvbuf[((size_t)b * N_G + g) * 72 + t] = o;
  }
}

// ---------------------------------------------------------------------------
// k_att: att^T f16. R17: for g>=32 the q-pw is inlined per pixel (fp32),
// weights read as wave-uniform global loads (L2-hot scalar loads). The
// g<32 / g>=32 branch is wave-uniform (gq = t>>5).
// ---------------------------------------------------------------------------
__global__ __launch_bounds__(256) void k_att(const f16* __restrict__ qkvh,
                                             const f16* __restrict__ dw,
                                             const float* __restrict__ wpw,
                                             const float* __restrict__ kvbuf,
                                             f16* __restrict__ atth) {
  __shared__ float skv[N_G * 72];
  __shared__ f16 sa[512][34];
  const int t = threadIdx.x;
  const int n0 = blockIdx.x * 32;
  const size_t b = blockIdx.y;
  for (int i = t; i < N_G * 72; i += 256) skv[i] = kvbuf[b * (N_G * 72) + i];
  __syncthreads();
  const int px = t & 31, gq = t >> 5;
#pragma unroll
  for (int gi = 0; gi < 8; ++gi) {
    const int g = gq * 8 + gi;
    float num[8] = {0.f, 0.f, 0.f, 0.f, 0.f, 0.f, 0.f, 0.f};
    float den = 0.f;
    const float* kvg0 = &skv[g * 72];
    if (g < 32) {
      const f16* qc = qkvh + ((size_t)b * TD3 + g * 24) * N_PIX + n0 + px;
#pragma unroll
      for (int d = 0; d < 8; ++d) {
        const float qd = fmaxf((float)qc[(size_t)d * N_PIX], 0.f);
        const float* kvg = kvg0 + d * 9;
#pragma unroll
        for (int e = 0; e < 8; ++e) num[e] = fmaf(qd, kvg[e], num[e]);
        den = fmaf(qd, kvg[8], den);
      }
    } else {
      const int gg = g - 32;
      const f16* dc = dw + ((size_t)b * TD3 + gg * 24) * N_PIX + n0 + px;
      const float* wq = wpw + (size_t)(gg * 3) * 64;  // q-group pw weights
      float dq[8];
#pragma unroll
      for (int ic = 0; ic < 8; ++ic) dq[ic] = (float)dc[(size_t)ic * N_PIX];
#pragma unroll
      for (int d = 0; d < 8; ++d) {
        float s = 0.f;
#pragma unroll
        for (int ic = 0; ic < 8; ++ic) s = fmaf(dq[ic], wq[d * 8 + ic], s);
        const float qd = fmaxf(s, 0.f);
        const float* kvg = kvg0 + d * 9;
#pragma unroll
        for (int e = 0; e < 8; ++e) num[e] = fmaf(qd, kvg[e], num[e]);
        den = fmaf(qd, kvg[8], den);
      }
    }
    const float rd = 1.f / (den + 1e-15f);
#pragma unroll
    for (int e = 0; e < 8; ++e) sa[g * 8 + e][px] = (f16)(num[e] * rd);
  }
  __syncthreads();
  f16* dst = atth + (b * N_PIX + n0) * 512;
  for (int i = 0; i < 64; ++i) {
    const int idx = t + i * 256;
    dst[idx] = sa[idx & 511][idx >> 9];
  }
}

// ---------------------------------------------------------------------------
extern "C" void kernel_launch(void* const* d_in, const int* in_sizes, int n_in,
                              void* d_out, int out_size, void* d_ws, size_t ws_size,
                              hipStream_t stream) {
  const float* x = (const float*)d_in[0];
  const float* w_qkv = (const float*)d_in[1];
  const float* w_dw = (const float*)d_in[2];
  const float* w_pw = (const float*)d_in[3];
  const float* w_proj = (const float*)d_in[4];
  float* out = (float*)d_out;

  char* ws = (char*)d_ws;
  size_t off = 0;
  f16* qkvh = (f16*)(ws + off); off += (size_t)N_B * TD3 * N_PIX * 2;   // 50.3 MB
  f16* dwbuf = (f16*)(ws + off); off += (size_t)N_B * TD3 * N_PIX * 2;  // 50.3 MB (was agg)
  float* kvbuf = (float*)(ws + off); off += (size_t)N_B * N_G * 72 * 4;
  f16* wqq_h = (f16*)(ws + off); off += (size_t)256 * C_IN * 2;
  f16* wqq_l = (f16*)(ws + off); off += (size_t)256 * C_IN * 2;
  f16* wqkv = (f16*)(ws + off); off += (size_t)512 * C_IN * 2;
  f16* wph = (f16*)(ws + off); off += (size_t)C_OUT * 512 * 2;
  // union region (disjoint lifetimes): xT(hi,lo) -> attT(single)
  f16* xTh = (f16*)(ws + off);
  f16* xTl = xTh + (size_t)N_B * N_PIX * C_IN;
  f16* atth = (f16*)(ws + off);

  k_prep<<<dim3(N_PIX / 64, C_IN / 64, N_B + 1), 256, 0, stream>>>(
      x, w_qkv, w_proj, xTh, xTl, wqq_h, wqq_l, wqkv, wph);
  k_gemmqkv<<<dim3(512 + 1024), 256, 0, stream>>>(
      wqq_h, wqq_l, wqkv, xTh, xTl, qkvh);
  k_dw<<<dim3(N_B * TD3), 256, 0, stream>>>(qkvh, w_dw, dwbuf);
  k_kv<<<dim3(N_G, N_B), 256, 0, stream>>>(qkvh, dwbuf, w_pw, kvbuf);
  k_att<<<dim3(N_PIX / 32, N_B), 256, 0, stream>>>(qkvh, dwbuf, w_pw, kvbuf, atth);
  k_gemm1<<<dim3(2 * 32 * N_B), 256, 0, stream>>>(wph, atth, out, C_OUT, 512);
}

// Round 19
// 143.085 us; speedup vs baseline: 1.0114x; 1.0114x over previous
//
#include <hip/hip_runtime.h>

#define N_PIX 4096
#define IMG_W 64
#define C_IN 256
#define TD3 768
#define N_B 8
#define N_G 64
#define C_OUT 256

typedef _Float16 f16;
typedef _Float16 half8 __attribute__((ext_vector_type(8)));
typedef _Float16 f16x4 __attribute__((ext_vector_type(4)));
typedef _Float16 f16x2 __attribute__((ext_vector_type(2)));
typedef float f32x4 __attribute__((ext_vector_type(4)));

// ---------------------------------------------------------------------------
// R19 = R16 verbatim (best verified: 143.3 µs, absmax 9.77e-4).
// R18's cooperative mega-kernel silently no-opped under graph capture
// (output stayed zero) — cooperative launch is not usable in this harness.
// ---------------------------------------------------------------------------

// ---------------------------------------------------------------------------
// k_prep: MERGED weight-convert + x-transpose.
// z < 8:  x -> xT (hi,lo) f16. hi/lo REQUIRED for q path (R6/R7: relu flips).
// z == 8: w_qkv -> wqq hi/lo (q) / wqkv hi (kv, 1-term safe); w_proj -> f16.
// ---------------------------------------------------------------------------
__global__ __launch_bounds__(256) void k_prep(const float* __restrict__ x,
                                              const float* __restrict__ wq,
                                              const float* __restrict__ wp,
                                              f16* __restrict__ xh,
                                              f16* __restrict__ xl,
                                              f16* __restrict__ wqq_h,
                                              f16* __restrict__ wqq_l,
                                              f16* __restrict__ wqkv,
                                              f16* __restrict__ wph) {
  const int t = threadIdx.x;
  if (blockIdx.z == 8) {
    const int bid = blockIdx.x + 64 * blockIdx.y;
    for (int i = bid * 256 + t; i < TD3 * C_IN + C_OUT * 512; i += 65536) {
      if (i < TD3 * C_IN) {
        const int r = i >> 8, k = i & 255;
        const float v = wq[i];
        const f16 h = (f16)v;
        const int g = r / 24, j = r % 24;
        if (j < 8) {
          const int qi = g * 8 + j;
          wqq_h[qi * 256 + k] = h;
          wqq_l[qi * 256 + k] = (f16)(v - (float)h);
        } else {
          const int kvi = g * 16 + (j - 8);
          wqkv[kvi * 256 + k] = h;
        }
      } else {
        const int j = i - TD3 * C_IN;
        wph[j] = (f16)wp[j];
      }
    }
    return;
  }
  __shared__ float st[64][65];
  const int n0 = blockIdx.x * 64;
  const int k0 = blockIdx.y * 64;
  const size_t b = blockIdx.z;
  const float* xb = x + b * (size_t)C_IN * N_PIX;
#pragma unroll
  for (int i = 0; i < 16; ++i) {
    const int idx = t + i * 256;
    const int r = idx >> 6, c = idx & 63;
    st[r][c] = xb[(size_t)(k0 + r) * N_PIX + n0 + c];
  }
  __syncthreads();
#pragma unroll
  for (int i = 0; i < 8; ++i) {
    const int idx = t + i * 256;
    const int n = idx >> 5, k2 = (idx & 31) * 2;
    const float v0 = st[k2][n], v1 = st[k2 + 1][n];
    const f16 h0 = (f16)v0, h1 = (f16)v1;
    const size_t o = (b * N_PIX + n0 + n) * C_IN + k0 + k2;
    *(f16x2*)(xh + o) = (f16x2){h0, h1};
    *(f16x2*)(xl + o) = (f16x2){(f16)(v0 - (float)h0), (f16)(v1 - (float)h1)};
  }
}

// ---------------------------------------------------------------------------
// k_gemmqkv: MERGED q-GEMM (3-term, BK=32) + kv-GEMM (1-term, BK=64).
// Blocks 0..511 = q path; 512..1535 = kv path. kv blocks backfill CUs as q
// blocks retire. Per-block math byte-identical to the R15 split kernels.
// ---------------------------------------------------------------------------
__global__ __launch_bounds__(256) void k_gemmqkv(const f16* __restrict__ Ah,
                                                 const f16* __restrict__ Al,
                                                 const f16* __restrict__ Akv,
                                                 const f16* __restrict__ Bh,
                                                 const f16* __restrict__ Bl,
                                                 f16* __restrict__ C) {
  __shared__ f16 sm[2][16384];
  const int t = threadIdx.x;
  const int lane = t & 63;
  const int w = t >> 6;

  if (blockIdx.x < 512) {
    const int bid = blockIdx.x;
    const int swz = (bid & 7) * 64 + (bid >> 3);
    const int mt = swz % 2;
    const int rest = swz / 2;
    const int nt = rest & 31;
    const size_t bz = rest >> 5;
    const int m0 = mt * 128;
    const int n0 = nt * 128;
    const int K = C_IN;

    const f16* Bhb = Bh + bz * (size_t)N_PIX * K;
    const f16* Blb = Bl + bz * (size_t)N_PIX * K;
    f16* Cb = C + bz * (size_t)TD3 * N_PIX;

    f32x4 acc[4][4];
#pragma unroll
    for (int i = 0; i < 4; ++i)
#pragma unroll
      for (int j = 0; j < 4; ++j) acc[i][j] = (f32x4){0.f, 0.f, 0.f, 0.f};

    const int wm = w >> 1, wn = w & 1;
    const int fr = lane & 15;
    const int fk = (lane >> 4) * 8;

    const f16* gsrc[8];
    int sslot[8];
#pragma unroll
    for (int i = 0; i < 8; ++i) {
      const int s = w + i * 4;
      const int frag = s & 7;
      const f16* base;
      int row0;
      if (s < 8) {
        base = Ah; row0 = m0;
      } else if (s < 16) {
        base = Al; row0 = m0;
      } else if (s < 24) {
        base = Bhb; row0 = n0;
      } else {
        base = Blb; row0 = n0;
      }
      gsrc[i] = base + (size_t)(row0 + frag * 16 + fr) * K + fk;
      sslot[i] = s * 512;
    }

#pragma unroll
    for (int i = 0; i < 8; ++i)
      __builtin_amdgcn_global_load_lds(
          (const __attribute__((address_space(1))) unsigned int*)gsrc[i],
          (__attribute__((address_space(3))) unsigned int*)&sm[0][sslot[i]], 16, 0, 0);

    int cur = 0;
    for (int tt = 0; tt < 8; ++tt) {
      if (tt + 1 < 8) {
#pragma unroll
        for (int i = 0; i < 8; ++i)
          __builtin_amdgcn_global_load_lds(
              (const __attribute__((address_space(1))) unsigned int*)(gsrc[i] + (tt + 1) * 32),
              (__attribute__((address_space(3))) unsigned int*)&sm[cur ^ 1][sslot[i]], 16, 0, 0);
        asm volatile("s_waitcnt vmcnt(8)" ::: "memory");
      } else {
        asm volatile("s_waitcnt vmcnt(0)" ::: "memory");
      }
      __builtin_amdgcn_s_barrier();
      const f16* smb = sm[cur];
      half8 ah[4], al[4], bh[4], bl[4];
#pragma unroll
      for (int mi = 0; mi < 4; ++mi) {
        ah[mi] = *(const half8*)&smb[(wm * 4 + mi) * 512 + lane * 8];
        al[mi] = *(const half8*)&smb[(8 + wm * 4 + mi) * 512 + lane * 8];
      }
#pragma unroll
      for (int ni = 0; ni < 4; ++ni) {
        bh[ni] = *(const half8*)&smb[(16 + wn * 4 + ni) * 512 + lane * 8];
        bl[ni] = *(const half8*)&smb[(24 + wn * 4 + ni) * 512 + lane * 8];
      }
#pragma unroll
      for (int mi = 0; mi < 4; ++mi)
#pragma unroll
        for (int ni = 0; ni < 4; ++ni) {
          acc[mi][ni] = __builtin_amdgcn_mfma_f32_16x16x32_f16(ah[mi], bh[ni], acc[mi][ni], 0, 0, 0);
          acc[mi][ni] = __builtin_amdgcn_mfma_f32_16x16x32_f16(ah[mi], bl[ni], acc[mi][ni], 0, 0, 0);
          acc[mi][ni] = __builtin_amdgcn_mfma_f32_16x16x32_f16(al[mi], bh[ni], acc[mi][ni], 0, 0, 0);
        }
      __builtin_amdgcn_s_barrier();
      cur ^= 1;
    }
    const int cr = (lane >> 4) * 4;
    const int cc = lane & 15;
#pragma unroll
    for (int mi = 0; mi < 4; ++mi)
#pragma unroll
      for (int ni = 0; ni < 4; ++ni) {
#pragma unroll
        for (int r = 0; r < 4; ++r) {
          const int row = m0 + wm * 64 + mi * 16 + cr + r;    // qrow in [0,256)
          const int ch = (row >> 3) * 24 + (row & 7);         // -> channel
          Cb[(size_t)ch * N_PIX + n0 + wn * 64 + ni * 16 + cc] = (f16)acc[mi][ni][r];
        }
      }
  } else {
    const int bid = blockIdx.x - 512;
    const int swz = (bid & 7) * 128 + (bid >> 3);
    const int mt = swz % 4;
    const int rest = swz / 4;
    const int nt = rest & 31;
    const size_t bz = rest >> 5;
    const int m0 = mt * 128;
    const int n0 = nt * 128;
    const int K = C_IN;

    const f16* Bb = Bh + bz * (size_t)N_PIX * K;
    f16* Cb = C + bz * (size_t)TD3 * N_PIX;

    f32x4 acc[4][4];
#pragma unroll
    for (int i = 0; i < 4; ++i)
#pragma unroll
      for (int j = 0; j < 4; ++j) acc[i][j] = (f32x4){0.f, 0.f, 0.f, 0.f};

    const int wm = w >> 1, wn = w & 1;
    const int fr2 = lane >> 3;
    const int fko = (lane & 7) * 8;
    const f16* gsrc[4][2];
    int sslot[4][2];
#pragma unroll
    for (int i = 0; i < 4; ++i) {
      const int s = w + i * 4;
      const int frag = s & 7;
      const f16* base = (s < 8) ? Akv : Bb;
      const int row0 = (s < 8) ? m0 : n0;
#pragma unroll
      for (int j = 0; j < 2; ++j) {
        gsrc[i][j] = base + (size_t)(row0 + frag * 16 + j * 8 + fr2) * K + fko;
        sslot[i][j] = s * 1024 + j * 512;
      }
    }

#pragma unroll
    for (int i = 0; i < 4; ++i)
#pragma unroll
      for (int j = 0; j < 2; ++j)
        __builtin_amdgcn_global_load_lds(
            (const __attribute__((address_space(1))) unsigned int*)gsrc[i][j],
            (__attribute__((address_space(3))) unsigned int*)&sm[0][sslot[i][j]], 16, 0, 0);

    int cur = 0;
    for (int tt = 0; tt < 4; ++tt) {
      if (tt + 1 < 4) {
#pragma unroll
        for (int i = 0; i < 4; ++i)
#pragma unroll
          for (int j = 0; j < 2; ++j)
            __builtin_amdgcn_global_load_lds(
                (const __attribute__((address_space(1))) unsigned int*)(gsrc[i][j] + (tt + 1) * 64),
                (__attribute__((address_space(3))) unsigned int*)&sm[cur ^ 1][sslot[i][j]], 16, 0, 0);
        asm volatile("s_waitcnt vmcnt(8)" ::: "memory");
      } else {
        asm volatile("s_waitcnt vmcnt(0)" ::: "memory");
      }
      __builtin_amdgcn_s_barrier();
      const f16* smb = sm[cur];
      const int fb = (lane & 15) * 64 + (lane >> 4) * 8;
      half8 av[4][2], bv[4][2];
#pragma unroll
      for (int mi = 0; mi < 4; ++mi)
#pragma unroll
        for (int kk = 0; kk < 2; ++kk)
          av[mi][kk] = *(const half8*)&smb[(wm * 4 + mi) * 1024 + fb + kk * 32];
#pragma unroll
      for (int ni = 0; ni < 4; ++ni)
#pragma unroll
        for (int kk = 0; kk < 2; ++kk)
          bv[ni][kk] = *(const half8*)&smb[(8 + wn * 4 + ni) * 1024 + fb + kk * 32];
#pragma unroll
      for (int kk = 0; kk < 2; ++kk)
#pragma unroll
        for (int mi = 0; mi < 4; ++mi)
#pragma unroll
          for (int ni = 0; ni < 4; ++ni)
            acc[mi][ni] = __builtin_amdgcn_mfma_f32_16x16x32_f16(av[mi][kk], bv[ni][kk], acc[mi][ni], 0, 0, 0);
      __builtin_amdgcn_s_barrier();
      cur ^= 1;
    }
    const int cr = (lane >> 4) * 4;
    const int cc = lane & 15;
#pragma unroll
    for (int mi = 0; mi < 4; ++mi)
#pragma unroll
      for (int ni = 0; ni < 4; ++ni) {
#pragma unroll
        for (int r = 0; r < 4; ++r) {
          const int row = m0 + wm * 64 + mi * 16 + cr + r;    // kvrow in [0,512)
          const int ch = (row >> 4) * 24 + 8 + (row & 15);    // -> channel
          Cb[(size_t)ch * N_PIX + n0 + wn * 64 + ni * 16 + cc] = (f16)acc[mi][ni][r];
        }
      }
  }
}

// ---------------------------------------------------------------------------
// k_gemm1: out = A[256][512] * B[b][4096][512]^T, 1-term f16, BK=64.
// ---------------------------------------------------------------------------
__global__ __launch_bounds__(256) void k_gemm1(const f16* __restrict__ A,
                                               const f16* __restrict__ B,
                                               float* __restrict__ C,
                                               int M, int K) {
  __shared__ f16 sm[2][16 * 1024];
  const int t = threadIdx.x;
  const int lane = t & 63;
  const int w = t >> 6;

  const int per = gridDim.x >> 3;
  const int swz = (blockIdx.x & 7) * per + (blockIdx.x >> 3);
  const int mtiles = M >> 7;  // 2
  const int mt = swz % mtiles;
  const int rest = swz / mtiles;
  const int nt = rest & 31;
  const size_t bz = rest >> 5;
  const int m0 = mt * 128;
  const int n0 = nt * 128;

  const f16* Bb = B + bz * (size_t)N_PIX * K;
  float* Cb = C + bz * (size_t)M * N_PIX;

  f32x4 acc[4][4];
#pragma unroll
  for (int i = 0; i < 4; ++i)
#pragma unroll
    for (int j = 0; j < 4; ++j) acc[i][j] = (f32x4){0.f, 0.f, 0.f, 0.f};

  const int wm = w >> 1, wn = w & 1;
  const int fr2 = lane >> 3;
  const int fko = (lane & 7) * 8;
  const f16* gsrc[4][2];
  int sslot[4][2];
#pragma unroll
  for (int i = 0; i < 4; ++i) {
    const int s = w + i * 4;
    const int frag = s & 7;
    const f16* base = (s < 8) ? A : Bb;
    const int row0 = (s < 8) ? m0 : n0;
#pragma unroll
    for (int j = 0; j < 2; ++j) {
      gsrc[i][j] = base + (size_t)(row0 + frag * 16 + j * 8 + fr2) * K + fko;
      sslot[i][j] = s * 1024 + j * 512;
    }
  }

#pragma unroll
  for (int i = 0; i < 4; ++i)
#pragma unroll
    for (int j = 0; j < 2; ++j)
      __builtin_amdgcn_global_load_lds(
          (const __attribute__((address_space(1))) unsigned int*)gsrc[i][j],
          (__attribute__((address_space(3))) unsigned int*)&sm[0][sslot[i][j]], 16, 0, 0);

  const int ntk = K / 64;  // 8
  int cur = 0;
  for (int tt = 0; tt < ntk; ++tt) {
    if (tt + 1 < ntk) {
#pragma unroll
      for (int i = 0; i < 4; ++i)
#pragma unroll
        for (int j = 0; j < 2; ++j)
          __builtin_amdgcn_global_load_lds(
              (const __attribute__((address_space(1))) unsigned int*)(gsrc[i][j] + (tt + 1) * 64),
              (__attribute__((address_space(3))) unsigned int*)&sm[cur ^ 1][sslot[i][j]], 16, 0, 0);
      asm volatile("s_waitcnt vmcnt(8)" ::: "memory");
    } else {
      asm volatile("s_waitcnt vmcnt(0)" ::: "memory");
    }
    __builtin_amdgcn_s_barrier();
    const f16* smb = sm[cur];
    const int fb = (lane & 15) * 64 + (lane >> 4) * 8;
    half8 av[4][2], bv[4][2];
#pragma unroll
    for (int mi = 0; mi < 4; ++mi)
#pragma unroll
      for (int kk = 0; kk < 2; ++kk)
        av[mi][kk] = *(const half8*)&smb[(wm * 4 + mi) * 1024 + fb + kk * 32];
#pragma unroll
    for (int ni = 0; ni < 4; ++ni)
#pragma unroll
      for (int kk = 0; kk < 2; ++kk)
        bv[ni][kk] = *(const half8*)&smb[(8 + wn * 4 + ni) * 1024 + fb + kk * 32];
#pragma unroll
    for (int kk = 0; kk < 2; ++kk)
#pragma unroll
      for (int mi = 0; mi < 4; ++mi)
#pragma unroll
        for (int ni = 0; ni < 4; ++ni)
          acc[mi][ni] = __builtin_amdgcn_mfma_f32_16x16x32_f16(av[mi][kk], bv[ni][kk], acc[mi][ni], 0, 0, 0);
    __builtin_amdgcn_s_barrier();
    cur ^= 1;
  }
  const int cr = (lane >> 4) * 4;
  const int cc = lane & 15;
#pragma unroll
  for (int mi = 0; mi < 4; ++mi)
#pragma unroll
    for (int ni = 0; ni < 4; ++ni) {
      float* p = Cb + (size_t)(m0 + wm * 64 + mi * 16 + cr) * N_PIX + n0 + wn * 64 + ni * 16 + cc;
#pragma unroll
      for (int r = 0; r < 4; ++r) p[(size_t)r * N_PIX] = acc[mi][ni][r];
    }
}

// ---------------------------------------------------------------------------
// k_dw: depthwise 5x5 (split form — fused dw+pw regressed twice: R3, R10).
// ---------------------------------------------------------------------------
__global__ __launch_bounds__(256) void k_dw(const f16* __restrict__ qkv,
                                            const float* __restrict__ wdw,
                                            f16* __restrict__ dw) {
  __shared__ float sin_[68][72];
  const int t = threadIdx.x;
  const int bc = blockIdx.x;
  const int ch = bc % TD3;
  const f16* src = qkv + (size_t)bc * N_PIX;

  for (int i = t; i < 68 * 72 / 4; i += 256) ((f32x4*)sin_)[i] = (f32x4){0.f, 0.f, 0.f, 0.f};
  float wreg[25];
#pragma unroll
  for (int i = 0; i < 25; ++i) wreg[i] = wdw[(size_t)ch * 25 + i];
  __syncthreads();
  for (int i = t; i < 512; i += 256) {
    const int r = i >> 3, c8 = (i & 7) * 8;
    const half8 p = *(const half8*)(src + r * 64 + c8);
    f32x4 lo = {(float)p[0], (float)p[1], (float)p[2], (float)p[3]};
    f32x4 hi = {(float)p[4], (float)p[5], (float)p[6], (float)p[7]};
    *(f32x4*)&sin_[r + 2][c8 + 4] = lo;
    *(f32x4*)&sin_[r + 2][c8 + 8] = hi;
  }
  __syncthreads();

  const int c = t & 63;
  const int rg = t >> 6;
  const int r0 = rg * 16;
  float win[5][5];
#pragma unroll
  for (int r = 0; r < 4; ++r)
#pragma unroll
    for (int j = 0; j < 5; ++j) win[r][j] = sin_[r0 + r][c + 2 + j];
#pragma unroll
  for (int orow = 0; orow < 16; ++orow) {
    const int slot = (orow + 4) % 5;
#pragma unroll
    for (int j = 0; j < 5; ++j) win[slot][j] = sin_[r0 + orow + 4][c + 2 + j];
    float s = 0.f;
#pragma unroll
    for (int dr = 0; dr < 5; ++dr) {
      const int rs = (orow + dr) % 5;
#pragma unroll
      for (int dc = 0; dc < 5; ++dc) s = fmaf(win[rs][dc], wreg[dr * 5 + dc], s);
    }
    dw[(size_t)bc * N_PIX + (r0 + orow) * 64 + c] = (f16)s;
  }
}

// ---------------------------------------------------------------------------
// k_pw: grouped pointwise 8->8, streaming.
// ---------------------------------------------------------------------------
__global__ __launch_bounds__(256) void k_pw(const f16* __restrict__ dw,
                                            const float* __restrict__ wpw,
                                            f16* __restrict__ agg) {
  const int t = threadIdx.x;
  const int q = blockIdx.x;
  const int bg = blockIdx.y;
  const int g = bg % 96;
  float wp[64];
#pragma unroll
  for (int i = 0; i < 64; ++i) wp[i] = wpw[(size_t)g * 64 + i];
  const size_t base = ((size_t)(bg / 96) * TD3 + g * 8) * N_PIX + q * 1024;
  const int px0 = t * 4;
  float dv[8][4];
#pragma unroll
  for (int ic = 0; ic < 8; ++ic) {
    const f16x4 v = *(const f16x4*)(dw + base + (size_t)ic * N_PIX + px0);
#pragma unroll
    for (int j = 0; j < 4; ++j) dv[ic][j] = (float)v[j];
  }
#pragma unroll
  for (int oc = 0; oc < 8; ++oc) {
    f16x4 o;
#pragma unroll
    for (int j = 0; j < 4; ++j) {
      float s = 0.f;
#pragma unroll
      for (int ic = 0; ic < 8; ++ic) s = fmaf(dv[ic][j], wp[oc * 8 + ic], s);
      o[j] = (f16)s;
    }
    *(f16x4*)(agg + base + (size_t)oc * N_PIX + px0) = o;
  }
}

// ---------------------------------------------------------------------------
// k_kv: kv[b][g][72] = sum_n relu(k)·vext, one block per (g,b), fp32 acc.
// Split-work xor butterfly (R13-proven).
// ---------------------------------------------------------------------------
__global__ __launch_bounds__(256, 1) void k_kv(const f16* __restrict__ qkv,
                                               const f16* __restrict__ agg,
                                               float* __restrict__ kvbuf) {
  const int t = threadIdx.x;
  const int g = blockIdx.x;
  const int b = blockIdx.y;
  const f16* src = (g < 32) ? qkv : agg;
  const int base = (g & 31) * 24;
  const f16* kc = src + ((size_t)b * TD3 + base + 8) * N_PIX;
  const f16* vc = src + ((size_t)b * TD3 + base + 16) * N_PIX;

  float acc[72];
#pragma unroll
  for (int i = 0; i < 72; i++) acc[i] = 0.f;

  for (int i = 0; i < N_PIX / 256; i++) {
    const int n = t + i * 256;
    float kd[8], ve[8];
#pragma unroll
    for (int d = 0; d < 8; d++) kd[d] = fmaxf((float)kc[(size_t)d * N_PIX + n], 0.f);
#pragma unroll
    for (int e = 0; e < 8; e++) ve[e] = (float)vc[(size_t)e * N_PIX + n];
#pragma unroll
    for (int d = 0; d < 8; d++) {
#pragma unroll
      for (int e = 0; e < 8; e++) acc[d * 9 + e] = fmaf(kd[d], ve[e], acc[d * 9 + e]);
      acc[d * 9 + 8] += kd[d];
    }
  }

  const int lane = t & 63, wv = t >> 6;
#pragma unroll
  for (int i = 0; i < 72; i++) acc[i] += __shfl_xor(acc[i], 32, 64);
  const int hi = lane >> 5;
  float r[36];
#pragma unroll
  for (int i = 0; i < 36; i++) r[i] = hi ? acc[36 + i] : acc[i];
#pragma unroll
  for (int off = 16; off >= 1; off >>= 1) {
#pragma unroll
    for (int i = 0; i < 36; i++) r[i] += __shfl_xor(r[i], off, 64);
  }
  __shared__ float red[4][72];
  if (lane == 0 || lane == 32) {
#pragma unroll
    for (int i = 0; i < 36; i++) red[wv][hi * 36 + i] = r[i];
  }
  __syncthreads();
  if (t < 72) {
    const float s = red[0][t] + red[1][t] + red[2][t] + red[3][t];
    kvbuf[((size_t)b * N_G + g) * 72 + t] = s;
  }
}

// ---------------------------------------------------------------------------
// k_att: att^T[b][4096][512] f16 (R13 form; att+proj fusion regressed R14).
// ---------------------------------------------------------------------------
__global__ __launch_bounds__(256) void k_att(const f16* __restrict__ qkvh,
                                             const f16* __restrict__ aggh,
                                             const float* __restrict__ kvbuf,
                                             f16* __restrict__ atth) {
  __shared__ float skv[N_G * 72];
  __shared__ f16 sa[512][34];
  const int t = threadIdx.x;
  const int n0 = blockIdx.x * 32;
  const size_t b = blockIdx.y;
  for (int i = t; i < N_G * 72; i += 256) skv[i] = kvbuf[b * (N_G * 72) + i];
  __syncthreads();
  const int px = t & 31, gq = t >> 5;
#pragma unroll
  for (int gi = 0; gi < 8; ++gi) {
    const int g = gq * 8 + gi;
    const f16* src = (g < 32) ? qkvh : aggh;
    const int base = (g & 31) * 24;
    const f16* qc = src + ((size_t)b * TD3 + base) * N_PIX + n0 + px;
    float num[8] = {0.f, 0.f, 0.f, 0.f, 0.f, 0.f, 0.f, 0.f};
    float den = 0.f;
#pragma unroll
    for (int d = 0; d < 8; ++d) {
      const float qd = fmaxf((float)qc[(size_t)d * N_PIX], 0.f);
      const float* kvg = &skv[g * 72 + d * 9];
#pragma unroll
      for (int e = 0; e < 8; ++e) num[e] = fmaf(qd, kvg[e], num[e]);
      den = fmaf(qd, kvg[8], den);
    }
    const float rd = 1.f / (den + 1e-15f);
#pragma unroll
    for (int e = 0; e < 8; ++e) sa[g * 8 + e][px] = (f16)(num[e] * rd);
  }
  __syncthreads();
  f16* dst = atth + (b * N_PIX + n0) * 512;
  for (int i = 0; i < 64; ++i) {
    const int idx = t + i * 256;
    dst[idx] = sa[idx & 511][idx >> 9];
  }
}

// ---------------------------------------------------------------------------
extern "C" void kernel_launch(void* const* d_in, const int* in_sizes, int n_in,
                              void* d_out, int out_size, void* d_ws, size_t ws_size,
                              hipStream_t stream) {
  const float* x = (const float*)d_in[0];
  const float* w_qkv = (const float*)d_in[1];
  const float* w_dw = (const float*)d_in[2];
  const float* w_pw = (const float*)d_in[3];
  const float* w_proj = (const float*)d_in[4];
  float* out = (float*)d_out;

  char* ws = (char*)d_ws;
  size_t off = 0;
  f16* qkvh = (f16*)(ws + off); off += (size_t)N_B * TD3 * N_PIX * 2;  // 50.3 MB
  f16* aggh = (f16*)(ws + off); off += (size_t)N_B * TD3 * N_PIX * 2;  // 50.3 MB
  float* kvbuf = (float*)(ws + off); off += (size_t)N_B * N_G * 72 * 4;
  f16* wqq_h = (f16*)(ws + off); off += (size_t)256 * C_IN * 2;
  f16* wqq_l = (f16*)(ws + off); off += (size_t)256 * C_IN * 2;
  f16* wqkv = (f16*)(ws + off); off += (size_t)512 * C_IN * 2;
  f16* wph = (f16*)(ws + off); off += (size_t)C_OUT * 512 * 2;
  // union region (disjoint lifetimes): xT(hi,lo) -> dwbuf -> attT(single)
  f16* xTh = (f16*)(ws + off);
  f16* xTl = xTh + (size_t)N_B * N_PIX * C_IN;
  f16* dwbuf = (f16*)(ws + off);
  f16* atth = (f16*)(ws + off);

  k_prep<<<dim3(N_PIX / 64, C_IN / 64, N_B + 1), 256, 0, stream>>>(
      x, w_qkv, w_proj, xTh, xTl, wqq_h, wqq_l, wqkv, wph);
  k_gemmqkv<<<dim3(512 + 1024), 256, 0, stream>>>(
      wqq_h, wqq_l, wqkv, xTh, xTl, qkvh);
  k_dw<<<dim3(N_B * TD3), 256, 0, stream>>>(qkvh, w_dw, dwbuf);
  k_pw<<<dim3(4, N_B * 96), 256, 0, stream>>>(dwbuf, w_pw, aggh);
  k_kv<<<dim3(N_G, N_B), 256, 0, stream>>>(qkvh, aggh, kvbuf);
  k_att<<<dim3(N_PIX / 32, N_B), 256, 0, stream>>>(qkvh, aggh, kvbuf, atth);
  k_gemm1<<<dim3(2 * 32 * N_B), 256, 0, stream>>>(wph, atth, out, C_OUT, 512);
}